// Round 1
// baseline (2068.567 us; speedup 1.0000x reference)
//
#include <hip/hip_runtime.h>
#include <math.h>

#define TT 2048
#define BBATCH 256
#define DDIM 57
#define NROWS (BBATCH*TT)
#define NF 524288.0f

__device__ __forceinline__ float bcastl(float v, int k) {
  // wave-wide broadcast of lane k's value via the scalar pipe (SGPR result)
  return __uint_as_float((unsigned)__builtin_amdgcn_readlane((int)__float_as_uint(v), k));
}
__device__ __forceinline__ float rcpf(float x) { return __builtin_amdgcn_rcpf(x); }

__global__ void zero_accum_k(float* accum) {
  accum[threadIdx.x] = 0.f;
}

// xg0[r, g] = sum_d x[r,d] * W_ih0[g,d] + (b_ih0[g] + b_hh0[g])
// one wave per row batch (grid-stride); W row in registers, x row via
// wave-uniform loads (scalar pipe / broadcast cached).
__global__ __launch_bounds__(256) void xg0_gemm_k(
    const float* __restrict__ x, const float* __restrict__ Wih,
    const float* __restrict__ bih, const float* __restrict__ bhh,
    float* __restrict__ xg0)
{
  const int lane = threadIdx.x & 63;
  const int wid  = blockIdx.x * (blockDim.x >> 6) + (threadIdx.x >> 6);
  const int nw   = gridDim.x * (blockDim.x >> 6);
  float w[DDIM];
  #pragma unroll
  for (int d = 0; d < DDIM; ++d) w[d] = Wih[lane*DDIM + d];
  const float bias = bih[lane] + bhh[lane];
  for (int r = wid; r < NROWS; r += nw) {
    const int ru = __builtin_amdgcn_readfirstlane(r);
    const float* xr = x + (size_t)ru * DDIM;
    float a0 = bias, a1 = 0.f, a2 = 0.f, a3 = 0.f;
    #pragma unroll
    for (int d = 0; d < 56; d += 4) {
      a0 += xr[d]   * w[d];
      a1 += xr[d+1] * w[d+1];
      a2 += xr[d+2] * w[d+2];
      a3 += xr[d+3] * w[d+3];
    }
    a0 += xr[56] * w[56];
    xg0[(size_t)ru * 64 + lane] = (a0 + a1) + (a2 + a3);
  }
}

// One wave (64 lanes) per batch element. Lane g computes gate g of 64
// (i:0-15, f:16-31, g:32-47, o:48-63) for all 3 layers each timestep.
// h/c state replicated per channel (ch = lane&15) on all 4 gate groups.
__global__ __launch_bounds__(64) void lstm_scan_k(
    const float* __restrict__ xg0,
    const int*   __restrict__ lengths,
    const float* __restrict__ Whh0,
    const float* __restrict__ Wih1, const float* __restrict__ Whh1,
    const float* __restrict__ bih1, const float* __restrict__ bhh1,
    const float* __restrict__ Wih2, const float* __restrict__ Whh2,
    const float* __restrict__ bih2, const float* __restrict__ bhh2,
    float* __restrict__ h2buf, float* __restrict__ accum)
{
  const int lane = threadIdx.x;
  const int b = blockIdx.x;
  const int len = lengths[b];
  const int ch = lane & 15;
  const bool isg = ((lane >> 4) == 2);

  float whh0[16], wih1[16], whh1[16], wih2[16], whh2[16];
  #pragma unroll
  for (int k = 0; k < 16; ++k) {
    whh0[k] = Whh0[lane*16 + k];
    wih1[k] = Wih1[lane*16 + k];
    whh1[k] = Whh1[lane*16 + k];
    wih2[k] = Wih2[lane*16 + k];
    whh2[k] = Whh2[lane*16 + k];
  }
  const float bias1 = bih1[lane] + bhh1[lane];
  const float bias2 = bih2[lane] + bhh2[lane];

  float h0=0.f,c0=0.f,h1=0.f,c1=0.f,h2=0.f,c2=0.f;
  float sum=0.f, sq=0.f;
  const int base = b*TT*64 + lane;
  float* __restrict__ h2row = h2buf + (size_t)b*TT*16;

  auto step = [&](float xg, int t) {
    // ---- layer 0 (input proj precomputed in xg) ----
    float a0 = xg, a1 = 0.f;
    #pragma unroll
    for (int k = 0; k < 16; k += 2) {
      a0 += whh0[k]   * bcastl(h0, k);
      a1 += whh0[k+1] * bcastl(h0, k+1);
    }
    float acc = a0 + a1;
    float arg = isg ? 2.f*acc : acc;
    float sg  = rcpf(1.f + __expf(-arg));
    float act = isg ? 2.f*sg - 1.f : sg;
    float gi = __shfl(act, ch,      64);
    float gf = __shfl(act, ch + 16, 64);
    float gg = __shfl(act, ch + 32, 64);
    float go = __shfl(act, ch + 48, 64);
    c0 = gf*c0 + gi*gg;
    h0 = go * (2.f*rcpf(1.f + __expf(-2.f*c0)) - 1.f);
    // ---- layer 1 ----
    float p0 = bias1, p1 = 0.f, p2 = 0.f, p3 = 0.f;
    #pragma unroll
    for (int k = 0; k < 16; k += 2) {
      p0 += wih1[k]   * bcastl(h0, k);
      p1 += wih1[k+1] * bcastl(h0, k+1);
      p2 += whh1[k]   * bcastl(h1, k);
      p3 += whh1[k+1] * bcastl(h1, k+1);
    }
    acc = (p0 + p1) + (p2 + p3);
    arg = isg ? 2.f*acc : acc;
    sg  = rcpf(1.f + __expf(-arg));
    act = isg ? 2.f*sg - 1.f : sg;
    gi = __shfl(act, ch, 64); gf = __shfl(act, ch+16, 64);
    gg = __shfl(act, ch+32, 64); go = __shfl(act, ch+48, 64);
    c1 = gf*c1 + gi*gg;
    h1 = go * (2.f*rcpf(1.f + __expf(-2.f*c1)) - 1.f);
    // ---- layer 2 ----
    float q0 = bias2, q1 = 0.f, q2 = 0.f, q3 = 0.f;
    #pragma unroll
    for (int k = 0; k < 16; k += 2) {
      q0 += wih2[k]   * bcastl(h1, k);
      q1 += wih2[k+1] * bcastl(h1, k+1);
      q2 += whh2[k]   * bcastl(h2, k);
      q3 += whh2[k+1] * bcastl(h2, k+1);
    }
    acc = (q0 + q1) + (q2 + q3);
    arg = isg ? 2.f*acc : acc;
    sg  = rcpf(1.f + __expf(-arg));
    act = isg ? 2.f*sg - 1.f : sg;
    gi = __shfl(act, ch, 64); gf = __shfl(act, ch+16, 64);
    gg = __shfl(act, ch+32, 64); go = __shfl(act, ch+48, 64);
    c2 = gf*c2 + gi*gg;
    h2 = go * (2.f*rcpf(1.f + __expf(-2.f*c2)) - 1.f);

    if (lane < 16) h2row[t*16 + lane] = h2;
    sum += h2; sq += h2*h2;
  };

  // software prefetch, distance 4 steps (~1400 cyc > worst-case HBM latency)
  float pf0 = xg0[base];
  float pf1 = xg0[base + 64];
  float pf2 = xg0[base + 128];
  float pf3 = xg0[base + 192];

  int t = 0;
  while (t + 4 <= len) {
    const int t4 = t + 4;
    int i0 = t4     > TT-1 ? TT-1 : t4;
    int i1 = t4 + 1 > TT-1 ? TT-1 : t4+1;
    int i2 = t4 + 2 > TT-1 ? TT-1 : t4+2;
    int i3 = t4 + 3 > TT-1 ? TT-1 : t4+3;
    float nf0 = xg0[base + i0*64];
    float nf1 = xg0[base + i1*64];
    float nf2 = xg0[base + i2*64];
    float nf3 = xg0[base + i3*64];
    step(pf0, t); step(pf1, t+1); step(pf2, t+2); step(pf3, t+3);
    pf0 = nf0; pf1 = nf1; pf2 = nf2; pf3 = nf3;
    t = t4;
  }
  for (; t < len; ++t) {       // <=3 tail steps, data already prefetched
    step(pf0, t);
    pf0 = pf1; pf1 = pf2; pf2 = pf3;
  }

  // zero padded region (masked positions) — coalesced full-wave stores
  for (int idx = len*16 + lane; idx < TT*16; idx += 64)
    h2row[idx] = 0.f;

  if (lane < 16) {
    atomicAdd(&accum[lane],      sum);
    atomicAdd(&accum[16 + lane], sq);
  }
}

// Fold BN (training-mode stats incl. padding zeros) + gamma/beta into FC:
// coef[o*16+c] = s_c * fc_w[o,c];  coef[64+o] = fc_b[o] + sum_c tb_c*fc_w[o,c]
__global__ void prep_k(const float* __restrict__ accum,
                       const float* __restrict__ gamma, const float* __restrict__ beta,
                       const float* __restrict__ fcw, const float* __restrict__ fcb,
                       float* __restrict__ coef)
{
  const int lane = threadIdx.x;          // 64 threads: o=lane>>4, c=lane&15
  const int o = lane >> 4, c = lane & 15;
  const float inv_n = 1.0f / NF;
  float mean = accum[c] * inv_n;
  float var  = accum[16 + c] * inv_n - mean*mean;
  float s  = gamma[c] * rsqrtf(var + 1e-5f);
  float tb = beta[c] - mean * s;
  float woc = fcw[o*16 + c];
  coef[lane] = s * woc;
  float term = tb * woc;
  #pragma unroll
  for (int off = 1; off < 16; off <<= 1) term += __shfl_xor(term, off, 16);
  if (c == 0) coef[64 + o] = fcb[o] + term;
}

__global__ __launch_bounds__(256) void finalize_k(
    const float* __restrict__ h2buf, const float* __restrict__ coef,
    float* __restrict__ out)
{
  const int r = blockIdx.x * 256 + threadIdx.x;
  const float4* hp = (const float4*)(h2buf + (size_t)r * 16);
  float4 v0 = hp[0], v1 = hp[1], v2 = hp[2], v3 = hp[3];
  float hv[16] = {v0.x,v0.y,v0.z,v0.w, v1.x,v1.y,v1.z,v1.w,
                  v2.x,v2.y,v2.z,v2.w, v3.x,v3.y,v3.z,v3.w};
  float4 o4;
  float* op = &o4.x;
  #pragma unroll
  for (int o = 0; o < 4; ++o) {
    float a = coef[64 + o];
    #pragma unroll
    for (int c = 0; c < 16; ++c) a += coef[o*16 + c] * hv[c];
    op[o] = a;
  }
  ((float4*)out)[r] = o4;
}

extern "C" void kernel_launch(void* const* d_in, const int* in_sizes, int n_in,
                              void* d_out, int out_size, void* d_ws, size_t ws_size,
                              hipStream_t stream)
{
  const float* x     = (const float*)d_in[0];
  const int* lengths = (const int*)d_in[1];
  const float* W_ih0 = (const float*)d_in[2];
  const float* b_ih0 = (const float*)d_in[4];
  const float* b_hh0 = (const float*)d_in[5];
  const float* W_hh0 = (const float*)d_in[3];
  const float* W_ih1 = (const float*)d_in[6];
  const float* W_hh1 = (const float*)d_in[7];
  const float* b_ih1 = (const float*)d_in[8];
  const float* b_hh1 = (const float*)d_in[9];
  const float* W_ih2 = (const float*)d_in[10];
  const float* W_hh2 = (const float*)d_in[11];
  const float* b_ih2 = (const float*)d_in[12];
  const float* b_hh2 = (const float*)d_in[13];
  const float* gamma = (const float*)d_in[14];
  const float* beta  = (const float*)d_in[15];
  const float* fcw   = (const float*)d_in[16];
  const float* fcb   = (const float*)d_in[17];
  float* out = (float*)d_out;

  float* ws    = (float*)d_ws;
  float* xg0   = ws;                        // B*T*64  = 33,554,432 floats (128 MB)
  float* h2    = ws + 33554432;             // B*T*16  =  8,388,608 floats (32 MB)
  float* accum = ws + 33554432 + 8388608;   // 32 floats
  float* coef  = accum + 32;                // 68 floats

  hipLaunchKernelGGL(zero_accum_k, dim3(1), dim3(32), 0, stream, accum);
  hipLaunchKernelGGL(xg0_gemm_k, dim3(1024), dim3(256), 0, stream,
                     x, W_ih0, b_ih0, b_hh0, xg0);
  hipLaunchKernelGGL(lstm_scan_k, dim3(256), dim3(64), 0, stream,
                     xg0, lengths, W_hh0, W_ih1, W_hh1, b_ih1, b_hh1,
                     W_ih2, W_hh2, b_ih2, b_hh2, h2, accum);
  hipLaunchKernelGGL(prep_k, dim3(1), dim3(64), 0, stream,
                     accum, gamma, beta, fcw, fcb, coef);
  hipLaunchKernelGGL(finalize_k, dim3(2048), dim3(256), 0, stream, h2, coef, out);
}